// Round 6
// baseline (359.866 us; speedup 1.0000x reference)
//
#include <hip/hip_runtime.h>

// LSTMnetwork: 3 sequential stages of h = lstm_act(inp @ Wp^T + b)
// M=8192, K=1024, packed N=3072 (f-gate dropped: i,g,o only).
// BM=256 x BN=192, BK=64, 512 thr (4wr x 2wc waves, wave-tile 64x96).
// A: LDS (xor-swizzle, dbuf 64KB). B: global->VGPR double-banked streams
// (L2-resident via T1 XCD swizzle) -- no LDS for B. One barrier per K-tile.

typedef float f32x4 __attribute__((ext_vector_type(4)));
typedef short short8 __attribute__((ext_vector_type(8)));
typedef unsigned short u16;

#define NP 3072
#define MROWS 8192
#define KDIM 1024
#define BM 256
#define BN 192
#define BK 64
#define LDS_A_SZ (BM * BK * 2)      // 32768 per buffer; dbuf = 65536

__device__ __forceinline__ u16 f2bf(float f) {
  unsigned u = __float_as_uint(f);
  u += 0x7fffu + ((u >> 16) & 1u);   // RTNE
  return (u16)(u >> 16);
}
__device__ __forceinline__ float sigmoid_f(float x) {
  return 1.0f / (1.0f + __expf(-x));
}
__device__ __forceinline__ float tanh_f(float x) {
  float xc = fminf(fmaxf(x, -15.0f), 15.0f);
  float e = __expf(2.0f * xc);
  return (e - 1.0f) / (e + 1.0f);
}
__device__ __forceinline__ void gload_lds16(const void* g, void* l) {
  __builtin_amdgcn_global_load_lds((const __attribute__((address_space(1))) void*)g,
                                   (__attribute__((address_space(3))) void*)l,
                                   16, 0, 0);
}

// ---------------- pre-passes (unchanged, verified) ----------------

__global__ __launch_bounds__(256) void k_convert_x(const float* __restrict__ x,
                                                   u16* __restrict__ out) {
  int tid = blockIdx.x * 256 + threadIdx.x;
  const float4* src = (const float4*)x + (size_t)tid * 2;
  float4 v0 = src[0], v1 = src[1];
  union { u16 u[8]; uint4 v; } r;
  r.u[0] = f2bf(v0.x); r.u[1] = f2bf(v0.y); r.u[2] = f2bf(v0.z); r.u[3] = f2bf(v0.w);
  r.u[4] = f2bf(v1.x); r.u[5] = f2bf(v1.y); r.u[6] = f2bf(v1.z); r.u[7] = f2bf(v1.w);
  ((uint4*)out)[tid] = r.v;
}

__global__ __launch_bounds__(256) void k_pack_w(const float* __restrict__ Wih0,
                                                const float* __restrict__ Wih12,
                                                u16* __restrict__ P) {
  int tid = blockIdx.x * 256 + threadIdx.x;
  int s   = tid / (NP * 128);
  int rem = tid - s * (NP * 128);
  int p   = rem >> 7;
  int k8  = rem & 127;
  int hb = p / 48;
  int pr = p - hb * 48;
  int gs = pr >> 4;
  int hl = pr & 15;
  int hcol = hb * 16 + hl;
  int dir = hcol >> 9;
  int h   = hcol & 511;
  int og  = (gs == 0) ? 0 : (gs + 1);     // 0->i, 1->g, 2->o
  const float* src;
  if (s == 0)
    src = Wih0 + ((size_t)(dir * 2048 + og * 512 + h)) * 1024 + k8 * 8;
  else
    src = Wih12 + ((size_t)(((s - 1) * 2 + dir) * 2048 + og * 512 + h)) * 1024 + k8 * 8;
  float4 v0 = ((const float4*)src)[0];
  float4 v1 = ((const float4*)src)[1];
  union { u16 u[8]; uint4 v; } r;
  r.u[0] = f2bf(v0.x); r.u[1] = f2bf(v0.y); r.u[2] = f2bf(v0.z); r.u[3] = f2bf(v0.w);
  r.u[4] = f2bf(v1.x); r.u[5] = f2bf(v1.y); r.u[6] = f2bf(v1.z); r.u[7] = f2bf(v1.w);
  ((uint4*)P)[tid] = r.v;
}

__global__ __launch_bounds__(256) void k_pack_bias(const float* __restrict__ bih0,
                                                   const float* __restrict__ bhh0,
                                                   const float* __restrict__ bih12,
                                                   const float* __restrict__ bhh12,
                                                   float* __restrict__ pb) {
  int tid = blockIdx.x * 256 + threadIdx.x;
  if (tid >= 3 * NP) return;
  int s = tid / NP;
  int p = tid - s * NP;
  int hb = p / 48;
  int pr = p - hb * 48;
  int gs = pr >> 4;
  int hl = pr & 15;
  int hcol = hb * 16 + hl;
  int dir = hcol >> 9;
  int h   = hcol & 511;
  int og  = (gs == 0) ? 0 : (gs + 1);
  int j   = og * 512 + h;
  float v;
  if (s == 0) {
    int i = dir * 2048 + j;
    v = bih0[i] + bhh0[i];
  } else {
    int i = ((s - 1) * 2 + dir) * 2048 + j;
    v = bih12[i] + bhh12[i];
  }
  pb[tid] = v;
}

// ---------------- fused GEMM + LSTM activation ----------------

#define BAR()    __builtin_amdgcn_s_barrier()
#define SCHEDB() __builtin_amdgcn_sched_barrier(0)
#define WAITV(N) asm volatile("s_waitcnt vmcnt(" #N ")" ::: "memory")
#define MM(Macc, Aop, Bop) Macc = __builtin_amdgcn_mfma_f32_16x16x32_bf16(Aop, Bop, Macc, 0, 0, 0)

// A fragment ds_read (swizzled slot in aK0/aK1 per-lane bases)
#define LDA0(M4) (*(const short8*)(lds + aK0 + ((M4) * 2048)))
#define LDA1(M4) (*(const short8*)(lds + aK1 + ((M4) * 2048)))
#define LDA0B(M4) (*(const short8*)(lds + LDS_A_SZ + aK0 + ((M4) * 2048)))
#define LDA1B(M4) (*(const short8*)(lds + LDS_A_SZ + aK1 + ((M4) * 2048)))

// A staging: one round = 512 thr x 16B = 8KB = 64 rows; linear LDS dest,
// inverse-swizzled source octet (rule 21: both-sides-or-neither).
#define STAGE_A(ROWB, BUF, KT) \
  gload_lds16(srcA + (size_t)(ROWB) * KDIM + (size_t)(KT) * BK, \
              lds + (BUF) * LDS_A_SZ + (ROWB) * 128 + t * 16)
#define STAGE_A4(BUF, KT) \
  STAGE_A(0, BUF, KT); STAGE_A(64, BUF, KT); STAGE_A(128, BUF, KT); STAGE_A(192, BUF, KT)

// B fragment: global->VGPR. element offset = n*16*KDIM + kt*64 + k32*32
#define BLOAD6(DST, KT, K32) \
  DST##0 = *(const short8*)(bB + 0 * 16 * KDIM + (KT) * 64 + (K32) * 32); \
  DST##1 = *(const short8*)(bB + 1 * 16 * KDIM + (KT) * 64 + (K32) * 32); \
  DST##2 = *(const short8*)(bB + 2 * 16 * KDIM + (KT) * 64 + (K32) * 32); \
  DST##3 = *(const short8*)(bB + 3 * 16 * KDIM + (KT) * 64 + (K32) * 32); \
  DST##4 = *(const short8*)(bB + 4 * 16 * KDIM + (KT) * 64 + (K32) * 32); \
  DST##5 = *(const short8*)(bB + 5 * 16 * KDIM + (KT) * 64 + (K32) * 32)

// 24 MFMA: 4 A-frags x 6 B-frags (one k32)
#define MM24(A0_, A1_, A2_, A3_, BB) \
  MM(acc[0][0], A0_, BB##0); MM(acc[1][0], A1_, BB##0); MM(acc[2][0], A2_, BB##0); MM(acc[3][0], A3_, BB##0); \
  MM(acc[0][1], A0_, BB##1); MM(acc[1][1], A1_, BB##1); MM(acc[2][1], A2_, BB##1); MM(acc[3][1], A3_, BB##1); \
  MM(acc[0][2], A0_, BB##2); MM(acc[1][2], A1_, BB##2); MM(acc[2][2], A2_, BB##2); MM(acc[3][2], A3_, BB##2); \
  MM(acc[0][3], A0_, BB##3); MM(acc[1][3], A1_, BB##3); MM(acc[2][3], A2_, BB##3); MM(acc[3][3], A3_, BB##3); \
  MM(acc[0][4], A0_, BB##4); MM(acc[1][4], A1_, BB##4); MM(acc[2][4], A2_, BB##4); MM(acc[3][4], A3_, BB##4); \
  MM(acc[0][5], A0_, BB##5); MM(acc[1][5], A1_, BB##5); MM(acc[2][5], A2_, BB##5); MM(acc[3][5], A3_, BB##5)

// One K-tile, one barrier. Sections pinned by SCHEDB so the vmcnt ledger
// holds: [4A stage][6 bqA loads][MFMA k0 (bqB, auto-vmcnt)][6 bqB loads]
// [MFMA k1 (bqA, auto-vmcnt drains the 4A too)][WAITV(6) -> A drained][BAR].
// bqB loads for tile n+1 issued ~half a tile before use (>> L2 latency).
#define TILE(BUF, KT, DO_STAGE) \
  { \
    if (DO_STAGE) { STAGE_A4((BUF)^1, (KT)+1); } \
    SCHEDB(); \
    BLOAD6(bqA, KT, 1); \
    SCHEDB(); \
    if (BUF) { aA0 = LDA0B(0); aA1 = LDA0B(1); aA2 = LDA0B(2); aA3 = LDA0B(3); } \
    else     { aA0 = LDA0(0);  aA1 = LDA0(1);  aA2 = LDA0(2);  aA3 = LDA0(3);  } \
    __builtin_amdgcn_s_setprio(1); \
    MM24(aA0, aA1, aA2, aA3, bqB); \
    __builtin_amdgcn_s_setprio(0); \
    SCHEDB(); \
    if (DO_STAGE) { BLOAD6(bqB, (KT)+1, 0); } \
    SCHEDB(); \
    if (BUF) { aA0 = LDA1B(0); aA1 = LDA1B(1); aA2 = LDA1B(2); aA3 = LDA1B(3); } \
    else     { aA0 = LDA1(0);  aA1 = LDA1(1);  aA2 = LDA1(2);  aA3 = LDA1(3);  } \
    __builtin_amdgcn_s_setprio(1); \
    MM24(aA0, aA1, aA2, aA3, bqA); \
    __builtin_amdgcn_s_setprio(0); \
    if (DO_STAGE) { WAITV(6); BAR(); } \
    SCHEDB(); \
  }

template <bool F32OUT>
__global__ __launch_bounds__(512, 2) void k_lstm_gemm8(const u16* __restrict__ A,
                                                       const u16* __restrict__ Bp,
                                                       const float* __restrict__ bias,
                                                       void* __restrict__ outp) {
  __shared__ __align__(16) char lds[2 * LDS_A_SZ];
  const int t    = threadIdx.x;
  const int lane = t & 63;
  const int w    = t >> 6;          // 0..7
  const int wr   = w >> 1;          // 0..3 (M: 64-row bands)
  const int wc   = w & 1;           // 0..1 (N: 96 packed cols)
  const int r16  = lane & 15, kg = lane >> 4;

  // T1: bijective XCD swizzle. XCD c owns an 8x8 rect (8 N-cols x 8 M-bands).
  const int n_hw = blockIdx.y * gridDim.x + blockIdx.x;
  const int c    = n_hw & 7;
  const int wlc  = n_hw >> 3;
  const int bx   = (c & 1) * 8 + (wlc & 7);    // 0..15
  const int by   = (c >> 1) * 8 + (wlc >> 3);  // 0..31
  const int brow = by * BM;
  const int bn0  = bx * BN;

  // per-lane swizzled A read bases: slot = (k32*4+kg) ^ (row&7)
  const int slot0 = kg ^ (r16 & 7);
  const int aK0 = wr * 8192 + r16 * 128 + slot0 * 16;
  const int aK1 = wr * 8192 + r16 * 128 + (slot0 ^ 4) * 16;

  // A staging source (inverse-permuted octet within each 128B row)
  const int rr   = t >> 3;                          // 0..63
  const int koct = ((t & 7) ^ (rr & 7)) << 3;
  const u16* srcA = A + (size_t)(brow + rr) * KDIM + koct;

  // B per-lane base: row = bn0 + wc*96 + n*16 + r16, octet kg
  const u16* bB = Bp + (size_t)(bn0 + wc * 96 + r16) * KDIM + kg * 8;

  f32x4 acc[4][6];
#pragma unroll
  for (int m = 0; m < 4; ++m)
#pragma unroll
    for (int n = 0; n < 6; ++n) acc[m][n] = (f32x4){0.f, 0.f, 0.f, 0.f};

  short8 aA0, aA1, aA2, aA3;
  short8 bqA0, bqA1, bqA2, bqA3, bqA4, bqA5;
  short8 bqB0, bqB1, bqB2, bqB3, bqB4, bqB5;

  // prologue: stage A tile0 -> buf0; load bqB (tile0 k0); drain A; barrier.
  STAGE_A4(0, 0);
  SCHEDB();
  BLOAD6(bqB, 0, 0);
  SCHEDB();
  WAITV(6);
  BAR(); SCHEDB();

  TILE(0, 0, 1);  TILE(1, 1, 1);  TILE(0, 2, 1);  TILE(1, 3, 1);
  TILE(0, 4, 1);  TILE(1, 5, 1);  TILE(0, 6, 1);  TILE(1, 7, 1);
  TILE(0, 8, 1);  TILE(1, 9, 1);  TILE(0, 10, 1); TILE(1, 11, 1);
  TILE(0, 12, 1); TILE(1, 13, 1); TILE(0, 14, 1); TILE(1, 15, 0);

  // epilogue: lane holds i,g,o (n = hb2*3 + gs) for hcol; rows per acc reg.
#pragma unroll
  for (int hb2 = 0; hb2 < 2; ++hb2) {
    int pbase = bn0 + wc * 96 + hb2 * 48;
    float biV = bias[pbase + r16];
    float bgV = bias[pbase + 16 + r16];
    float boV = bias[pbase + 32 + r16];
    int hcol = (pbase / 48) * 16 + r16;
#pragma unroll
    for (int m = 0; m < 4; ++m) {
      int rowb = brow + wr * 64 + m * 16 + kg * 4;
#pragma unroll
      for (int r = 0; r < 4; ++r) {
        float vi = acc[m][hb2 * 3 + 0][r] + biV;
        float vg = acc[m][hb2 * 3 + 1][r] + bgV;
        float vo = acc[m][hb2 * 3 + 2][r] + boV;
        float c2 = sigmoid_f(vi) * tanh_f(vg);
        float hv = sigmoid_f(vo) * tanh_f(c2);
        size_t oidx = (size_t)(rowb + r) * 1024 + hcol;
        if (F32OUT) ((float*)outp)[oidx] = hv;
        else        ((u16*)outp)[oidx]   = f2bf(hv);
      }
    }
  }
}

// ---------------- launch ----------------
extern "C" void kernel_launch(void* const* d_in, const int* in_sizes, int n_in,
                              void* d_out, int out_size, void* d_ws, size_t ws_size,
                              hipStream_t stream) {
  const float* x     = (const float*)d_in[0];
  const float* Wih0  = (const float*)d_in[1];
  const float* bih0  = (const float*)d_in[3];
  const float* bhh0  = (const float*)d_in[4];
  const float* Wih12 = (const float*)d_in[5];
  const float* bih12 = (const float*)d_in[7];
  const float* bhh12 = (const float*)d_in[8];

  char* ws = (char*)d_ws;
  u16*   xbf = (u16*)ws;                       // 16,777,216 B
  u16*   h1  = (u16*)(ws + 16777216);          // 16,777,216 B
  u16*   h2  = (u16*)(ws + 33554432);          // 16,777,216 B
  u16*   P3  = (u16*)(ws + 50331648);          // 18,874,368 B
  float* pb3 = (float*)(ws + 69206016);        // 36,864 B

  k_convert_x<<<4096, 256, 0, stream>>>(x, xbf);
  k_pack_w<<<4608, 256, 0, stream>>>(Wih0, Wih12, P3);
  k_pack_bias<<<36, 256, 0, stream>>>(bih0, bhh0, bih12, bhh12, pb3);

  dim3 grid(NP / BN, MROWS / BM);   // (16, 32) = 512 blocks = 2 exact CU rounds
  k_lstm_gemm8<false><<<grid, 512, 0, stream>>>(xbf, P3, pb3, h1);
  k_lstm_gemm8<false><<<grid, 512, 0, stream>>>(h1, P3 + (size_t)NP * KDIM, pb3 + NP, h2);
  k_lstm_gemm8<true ><<<grid, 512, 0, stream>>>(h2, P3 + (size_t)2 * NP * KDIM, pb3 + 2 * NP, d_out);
}

// Round 7
// 233.024 us; speedup vs baseline: 1.5443x; 1.5443x over previous
//
#include <hip/hip_runtime.h>

// LSTMnetwork: 3 sequential stages of h = lstm_act(inp @ Wp^T + b)
// M=8192, K=1024, packed N=3072 (f-gate dropped: i,g,o only).
// m97-class structure, occupancy-first: BM=128 x BN=96, BK=32, 256 thr
// (2x2 waves, wave-tile 64x48, acc[4][3]), LDS 28KB dbuf, plain
// __syncthreads() rhythm, __launch_bounds__(256,4) -> 4 blocks/CU
// (cross-block wave overlap covers barrier/vmcnt drains, m114/m97).

typedef float f32x4 __attribute__((ext_vector_type(4)));
typedef short short8 __attribute__((ext_vector_type(8)));
typedef unsigned short u16;

#define NP 3072
#define MROWS 8192
#define KDIM 1024
#define BM 128
#define BN 96
#define BK 32
#define LDS_TILE 14336              // A 8KB + B 6KB per buffer

__device__ __forceinline__ u16 f2bf(float f) {
  unsigned u = __float_as_uint(f);
  u += 0x7fffu + ((u >> 16) & 1u);   // RTNE
  return (u16)(u >> 16);
}
__device__ __forceinline__ float sigmoid_f(float x) {
  return 1.0f / (1.0f + __expf(-x));
}
__device__ __forceinline__ float tanh_f(float x) {
  float xc = fminf(fmaxf(x, -15.0f), 15.0f);
  float e = __expf(2.0f * xc);
  return (e - 1.0f) / (e + 1.0f);
}
__device__ __forceinline__ void gload_lds16(const void* g, void* l) {
  __builtin_amdgcn_global_load_lds((const __attribute__((address_space(1))) void*)g,
                                   (__attribute__((address_space(3))) void*)l,
                                   16, 0, 0);
}

// ---------------- pre-passes (unchanged, verified) ----------------

__global__ __launch_bounds__(256) void k_convert_x(const float* __restrict__ x,
                                                   u16* __restrict__ out) {
  int tid = blockIdx.x * 256 + threadIdx.x;
  const float4* src = (const float4*)x + (size_t)tid * 2;
  float4 v0 = src[0], v1 = src[1];
  union { u16 u[8]; uint4 v; } r;
  r.u[0] = f2bf(v0.x); r.u[1] = f2bf(v0.y); r.u[2] = f2bf(v0.z); r.u[3] = f2bf(v0.w);
  r.u[4] = f2bf(v1.x); r.u[5] = f2bf(v1.y); r.u[6] = f2bf(v1.z); r.u[7] = f2bf(v1.w);
  ((uint4*)out)[tid] = r.v;
}

__global__ __launch_bounds__(256) void k_pack_w(const float* __restrict__ Wih0,
                                                const float* __restrict__ Wih12,
                                                u16* __restrict__ P) {
  int tid = blockIdx.x * 256 + threadIdx.x;
  int s   = tid / (NP * 128);
  int rem = tid - s * (NP * 128);
  int p   = rem >> 7;
  int k8  = rem & 127;
  int hb = p / 48;
  int pr = p - hb * 48;
  int gs = pr >> 4;
  int hl = pr & 15;
  int hcol = hb * 16 + hl;
  int dir = hcol >> 9;
  int h   = hcol & 511;
  int og  = (gs == 0) ? 0 : (gs + 1);     // 0->i, 1->g, 2->o
  const float* src;
  if (s == 0)
    src = Wih0 + ((size_t)(dir * 2048 + og * 512 + h)) * 1024 + k8 * 8;
  else
    src = Wih12 + ((size_t)(((s - 1) * 2 + dir) * 2048 + og * 512 + h)) * 1024 + k8 * 8;
  float4 v0 = ((const float4*)src)[0];
  float4 v1 = ((const float4*)src)[1];
  union { u16 u[8]; uint4 v; } r;
  r.u[0] = f2bf(v0.x); r.u[1] = f2bf(v0.y); r.u[2] = f2bf(v0.z); r.u[3] = f2bf(v0.w);
  r.u[4] = f2bf(v1.x); r.u[5] = f2bf(v1.y); r.u[6] = f2bf(v1.z); r.u[7] = f2bf(v1.w);
  ((uint4*)P)[tid] = r.v;
}

__global__ __launch_bounds__(256) void k_pack_bias(const float* __restrict__ bih0,
                                                   const float* __restrict__ bhh0,
                                                   const float* __restrict__ bih12,
                                                   const float* __restrict__ bhh12,
                                                   float* __restrict__ pb) {
  int tid = blockIdx.x * 256 + threadIdx.x;
  if (tid >= 3 * NP) return;
  int s = tid / NP;
  int p = tid - s * NP;
  int hb = p / 48;
  int pr = p - hb * 48;
  int gs = pr >> 4;
  int hl = pr & 15;
  int hcol = hb * 16 + hl;
  int dir = hcol >> 9;
  int h   = hcol & 511;
  int og  = (gs == 0) ? 0 : (gs + 1);
  int j   = og * 512 + h;
  float v;
  if (s == 0) {
    int i = dir * 2048 + j;
    v = bih0[i] + bhh0[i];
  } else {
    int i = ((s - 1) * 2 + dir) * 2048 + j;
    v = bih12[i] + bhh12[i];
  }
  pb[tid] = v;
}

// ---------------- fused GEMM + LSTM activation ----------------

#define MM(Macc, Aop, Bop) Macc = __builtin_amdgcn_mfma_f32_16x16x32_bf16(Aop, Bop, Macc, 0, 0, 0)

// Staging: linear LDS dest (rule 21), inverse-swizzled source octet.
// Slot layout: row r, 16B slot s at byte (r*4+s)*16; slot s holds k-octet
// s ^ ((r>>1)&3). Per-lane: row = t>>2 (+64 for second A inst / second B
// inst), slot = t&3; source octet xor = ((t&3) ^ ((t>>3)&3)) (it-invariant
// since 64-row steps shift (r>>1) by 32 == 0 mod 4).
#define STAGE(BUF, KT) \
  gload_lds16(srcA + (size_t)(KT) * BK,              lds + (BUF) * LDS_TILE + t * 16); \
  gload_lds16(srcA + 64 * KDIM + (size_t)(KT) * BK,  lds + (BUF) * LDS_TILE + 4096 + t * 16); \
  gload_lds16(srcB + (size_t)(KT) * BK,              lds + (BUF) * LDS_TILE + 8192 + t * 16); \
  if (t < 128) { gload_lds16(srcB + 64 * KDIM + (size_t)(KT) * BK, lds + (BUF) * LDS_TILE + 12288 + t * 16); }

// One K-step (BK=32): stage next tile, read 4 A + 3 B frags, 12 MFMA, sync.
#define KSTEP(BUF, KT, DOST) \
  { \
    if (DOST) { STAGE((BUF)^1, (KT)+1); } \
    const char* base = lds + (BUF) * LDS_TILE; \
    short8 a0 = *(const short8*)(base + aOff); \
    short8 a1 = *(const short8*)(base + aOff + 1024); \
    short8 a2 = *(const short8*)(base + aOff + 2048); \
    short8 a3 = *(const short8*)(base + aOff + 3072); \
    short8 b0 = *(const short8*)(base + bOff); \
    short8 b1 = *(const short8*)(base + bOff + 1024); \
    short8 b2 = *(const short8*)(base + bOff + 2048); \
    MM(acc[0][0], a0, b0); MM(acc[1][0], a1, b0); MM(acc[2][0], a2, b0); MM(acc[3][0], a3, b0); \
    MM(acc[0][1], a0, b1); MM(acc[1][1], a1, b1); MM(acc[2][1], a2, b1); MM(acc[3][1], a3, b1); \
    MM(acc[0][2], a0, b2); MM(acc[1][2], a1, b2); MM(acc[2][2], a2, b2); MM(acc[3][2], a3, b2); \
    __syncthreads(); \
  }

template <bool F32OUT>
__global__ __launch_bounds__(256, 4) void k_lstm_gemm97(const u16* __restrict__ A,
                                                        const u16* __restrict__ Bp,
                                                        const float* __restrict__ bias,
                                                        void* __restrict__ outp) {
  __shared__ __align__(16) char lds[2 * LDS_TILE];   // 28 KB
  const int t    = threadIdx.x;
  const int lane = t & 63;
  const int w    = t >> 6;          // 0..3
  const int wr   = w >> 1;          // 0..1 (M half: 64 rows)
  const int wc   = w & 1;           // 0..1 (N half: 48 packed cols = 1 trio)
  const int r16  = lane & 15, kg = lane >> 4;

  // T1: bijective XCD swizzle; grid 32x64 = 2048 = 8 x 256. XCD c owns a
  // 16x16 rect of (N-col, M-band) tiles.
  const int n_hw = blockIdx.y * gridDim.x + blockIdx.x;
  const int c    = n_hw & 7;
  const int wlc  = n_hw >> 3;          // 0..255
  const int bx   = (c & 1) * 16 + (wlc & 15);    // 0..31
  const int by   = (c >> 1) * 16 + (wlc >> 4);   // 0..63
  const int brow = by * BM;
  const int bn0  = bx * BN;

  // per-lane swizzled read bases: slot = kg ^ ((row>>1)&3), row%2 folded out
  const int sw   = (r16 >> 1) & 3;
  const int slot = (kg ^ sw) << 4;
  const int aOff = wr * 4096 + r16 * 64 + slot;           // + m*1024
  const int bOff = 8192 + wc * 3072 + r16 * 64 + slot;    // + n*1024

  // staging source (inverse-permuted octet within each 64B row)
  const int srow = t >> 2;
  const int koct = ((t & 3) ^ ((t >> 3) & 3)) << 3;
  const u16* srcA = A  + (size_t)(brow + srow) * KDIM + koct;
  const u16* srcB = Bp + (size_t)(bn0  + srow) * KDIM + koct;

  f32x4 acc[4][3];
#pragma unroll
  for (int m = 0; m < 4; ++m)
#pragma unroll
    for (int n = 0; n < 3; ++n) acc[m][n] = (f32x4){0.f, 0.f, 0.f, 0.f};

  STAGE(0, 0);
  __syncthreads();

  for (int k2 = 0; k2 < 15; ++k2) {
    KSTEP(0, 2 * k2, 1);
    KSTEP(1, 2 * k2 + 1, 1);
  }
  KSTEP(0, 30, 1);
  KSTEP(1, 31, 0);

  // epilogue: wave owns one gate-trio (48 packed cols); lane holds i,g,o
  // for hcol in acc[m][0..2].
  {
    int pbase = bn0 + wc * 48;
    float biV = bias[pbase + r16];
    float bgV = bias[pbase + 16 + r16];
    float boV = bias[pbase + 32 + r16];
    int hcol = (2 * bx + wc) * 16 + r16;
#pragma unroll
    for (int m = 0; m < 4; ++m) {
      int rowb = brow + wr * 64 + m * 16 + kg * 4;
#pragma unroll
      for (int r = 0; r < 4; ++r) {
        float vi = acc[m][0][r] + biV;
        float vg = acc[m][1][r] + bgV;
        float vo = acc[m][2][r] + boV;
        float c2 = sigmoid_f(vi) * tanh_f(vg);
        float hv = sigmoid_f(vo) * tanh_f(c2);
        size_t oidx = (size_t)(rowb + r) * 1024 + hcol;
        if (F32OUT) ((float*)outp)[oidx] = hv;
        else        ((u16*)outp)[oidx]   = f2bf(hv);
      }
    }
  }
}

// ---------------- launch ----------------
extern "C" void kernel_launch(void* const* d_in, const int* in_sizes, int n_in,
                              void* d_out, int out_size, void* d_ws, size_t ws_size,
                              hipStream_t stream) {
  const float* x     = (const float*)d_in[0];
  const float* Wih0  = (const float*)d_in[1];
  const float* bih0  = (const float*)d_in[3];
  const float* bhh0  = (const float*)d_in[4];
  const float* Wih12 = (const float*)d_in[5];
  const float* bih12 = (const float*)d_in[7];
  const float* bhh12 = (const float*)d_in[8];

  char* ws = (char*)d_ws;
  u16*   xbf = (u16*)ws;                       // 16,777,216 B
  u16*   h1  = (u16*)(ws + 16777216);          // 16,777,216 B
  u16*   h2  = (u16*)(ws + 33554432);          // 16,777,216 B
  u16*   P3  = (u16*)(ws + 50331648);          // 18,874,368 B
  float* pb3 = (float*)(ws + 69206016);        // 36,864 B

  k_convert_x<<<4096, 256, 0, stream>>>(x, xbf);
  k_pack_w<<<4608, 256, 0, stream>>>(Wih0, Wih12, P3);
  k_pack_bias<<<36, 256, 0, stream>>>(bih0, bhh0, bih12, bhh12, pb3);

  dim3 grid(NP / BN, MROWS / BM);   // (32, 64) = 2048 blocks, 4 blocks/CU
  k_lstm_gemm97<false><<<grid, 256, 0, stream>>>(xbf, P3, pb3, h1);
  k_lstm_gemm97<false><<<grid, 256, 0, stream>>>(h1, P3 + (size_t)NP * KDIM, pb3 + NP, h2);
  k_lstm_gemm97<true ><<<grid, 256, 0, stream>>>(h2, P3 + (size_t)2 * NP * KDIM, pb3 + 2 * NP, d_out);
}

// Round 8
// 232.159 us; speedup vs baseline: 1.5501x; 1.0037x over previous
//
#include <hip/hip_runtime.h>

// LSTMnetwork: 3 sequential stages of h = lstm_act(inp @ Wp^T + b)
// M=8192, K=1024, packed N=3072 (f-gate dropped: i,g,o only).
// BM=128 x BN=96, BK=32, 256 thr (2x2 waves, wave-tile 64x48, acc[4][3]).
// LDS TRI-buffer (42KB): tile kt stages kt+2 -> 2-tile prefetch depth, so
// each staging group has a full tile in flight before its counted wait.
// Raw s_barrier + per-wave counted WAITV (no compiler vmcnt(0) drain).
// 3 blocks/CU; T1 XCD rect swizzle; T2 xor-swizzle on A and B.

typedef float f32x4 __attribute__((ext_vector_type(4)));
typedef short short8 __attribute__((ext_vector_type(8)));
typedef unsigned short u16;

#define NP 3072
#define MROWS 8192
#define KDIM 1024
#define BM 128
#define BN 96
#define BK 32
#define LDS_TILE 14336              // A 8KB + B 6KB per buffer; x3 = 42KB

__device__ __forceinline__ u16 f2bf(float f) {
  unsigned u = __float_as_uint(f);
  u += 0x7fffu + ((u >> 16) & 1u);   // RTNE
  return (u16)(u >> 16);
}
__device__ __forceinline__ float sigmoid_f(float x) {
  return 1.0f / (1.0f + __expf(-x));
}
__device__ __forceinline__ float tanh_f(float x) {
  float xc = fminf(fmaxf(x, -15.0f), 15.0f);
  float e = __expf(2.0f * xc);
  return (e - 1.0f) / (e + 1.0f);
}
__device__ __forceinline__ void gload_lds16(const void* g, void* l) {
  __builtin_amdgcn_global_load_lds((const __attribute__((address_space(1))) void*)g,
                                   (__attribute__((address_space(3))) void*)l,
                                   16, 0, 0);
}

// ---------------- pre-passes (unchanged, verified) ----------------

__global__ __launch_bounds__(256) void k_convert_x(const float* __restrict__ x,
                                                   u16* __restrict__ out) {
  int tid = blockIdx.x * 256 + threadIdx.x;
  const float4* src = (const float4*)x + (size_t)tid * 2;
  float4 v0 = src[0], v1 = src[1];
  union { u16 u[8]; uint4 v; } r;
  r.u[0] = f2bf(v0.x); r.u[1] = f2bf(v0.y); r.u[2] = f2bf(v0.z); r.u[3] = f2bf(v0.w);
  r.u[4] = f2bf(v1.x); r.u[5] = f2bf(v1.y); r.u[6] = f2bf(v1.z); r.u[7] = f2bf(v1.w);
  ((uint4*)out)[tid] = r.v;
}

__global__ __launch_bounds__(256) void k_pack_w(const float* __restrict__ Wih0,
                                                const float* __restrict__ Wih12,
                                                u16* __restrict__ P) {
  int tid = blockIdx.x * 256 + threadIdx.x;
  int s   = tid / (NP * 128);
  int rem = tid - s * (NP * 128);
  int p   = rem >> 7;
  int k8  = rem & 127;
  int hb = p / 48;
  int pr = p - hb * 48;
  int gs = pr >> 4;
  int hl = pr & 15;
  int hcol = hb * 16 + hl;
  int dir = hcol >> 9;
  int h   = hcol & 511;
  int og  = (gs == 0) ? 0 : (gs + 1);     // 0->i, 1->g, 2->o
  const float* src;
  if (s == 0)
    src = Wih0 + ((size_t)(dir * 2048 + og * 512 + h)) * 1024 + k8 * 8;
  else
    src = Wih12 + ((size_t)(((s - 1) * 2 + dir) * 2048 + og * 512 + h)) * 1024 + k8 * 8;
  float4 v0 = ((const float4*)src)[0];
  float4 v1 = ((const float4*)src)[1];
  union { u16 u[8]; uint4 v; } r;
  r.u[0] = f2bf(v0.x); r.u[1] = f2bf(v0.y); r.u[2] = f2bf(v0.z); r.u[3] = f2bf(v0.w);
  r.u[4] = f2bf(v1.x); r.u[5] = f2bf(v1.y); r.u[6] = f2bf(v1.z); r.u[7] = f2bf(v1.w);
  ((uint4*)P)[tid] = r.v;
}

__global__ __launch_bounds__(256) void k_pack_bias(const float* __restrict__ bih0,
                                                   const float* __restrict__ bhh0,
                                                   const float* __restrict__ bih12,
                                                   const float* __restrict__ bhh12,
                                                   float* __restrict__ pb) {
  int tid = blockIdx.x * 256 + threadIdx.x;
  if (tid >= 3 * NP) return;
  int s = tid / NP;
  int p = tid - s * NP;
  int hb = p / 48;
  int pr = p - hb * 48;
  int gs = pr >> 4;
  int hl = pr & 15;
  int hcol = hb * 16 + hl;
  int dir = hcol >> 9;
  int h   = hcol & 511;
  int og  = (gs == 0) ? 0 : (gs + 1);
  int j   = og * 512 + h;
  float v;
  if (s == 0) {
    int i = dir * 2048 + j;
    v = bih0[i] + bhh0[i];
  } else {
    int i = ((s - 1) * 2 + dir) * 2048 + j;
    v = bih12[i] + bhh12[i];
  }
  pb[tid] = v;
}

// ---------------- fused GEMM + LSTM activation ----------------

#define BAR()    __builtin_amdgcn_s_barrier()
#define SCHEDB() __builtin_amdgcn_sched_barrier(0)
#define WAITV(N) asm volatile("s_waitcnt vmcnt(" #N ")" ::: "memory")
#define MM(Macc, Aop, Bop) Macc = __builtin_amdgcn_mfma_f32_16x16x32_bf16(Aop, Bop, Macc, 0, 0, 0)

// Stage tile KT into buffer BUF. Linear LDS dest (rule 21), inverse-swizzled
// source octet. Waves 0/1 issue 4 loads, waves 2/3 issue 3 (t<128 cond is
// wave-uniform); counted waits are per-wave adjusted (WAITV 4 vs 3).
#define STAGE(BUF, KT) \
  gload_lds16(srcA + (size_t)(KT) * BK,              lds + (BUF) * LDS_TILE + t * 16); \
  gload_lds16(srcA + 64 * KDIM + (size_t)(KT) * BK,  lds + (BUF) * LDS_TILE + 4096 + t * 16); \
  gload_lds16(srcB + (size_t)(KT) * BK,              lds + (BUF) * LDS_TILE + 8192 + t * 16); \
  if (t < 128) { gload_lds16(srcB + 64 * KDIM + (size_t)(KT) * BK, lds + (BUF) * LDS_TILE + 12288 + t * 16); }

// Per-wave group size: G=4 (waves 0,1), G=3 (waves 2,3). Steady state: at
// tile entry 1 group outstanding (g_{kt+1}); issue g_{kt+2} -> 2 groups;
// WAITV(G) drains g_{kt+1}, leaves g_{kt+2}. Tail: tile 30 WAITV(0) drains
// g31; tile 31 computes and falls through to epilogue.
#define KSTEP(RBUF, SBUF, KT, DOST, LASTT) \
  { \
    if (DOST) { STAGE(SBUF, (KT) + 2); } \
    const char* base = lds + (RBUF) * LDS_TILE; \
    short8 a0 = *(const short8*)(base + aOff); \
    short8 a1 = *(const short8*)(base + aOff + 1024); \
    short8 a2 = *(const short8*)(base + aOff + 2048); \
    short8 a3 = *(const short8*)(base + aOff + 3072); \
    short8 b0 = *(const short8*)(base + bOff); \
    short8 b1 = *(const short8*)(base + bOff + 1024); \
    short8 b2 = *(const short8*)(base + bOff + 2048); \
    __builtin_amdgcn_s_setprio(1); \
    MM(acc[0][0], a0, b0); MM(acc[1][0], a1, b0); MM(acc[2][0], a2, b0); MM(acc[3][0], a3, b0); \
    MM(acc[0][1], a0, b1); MM(acc[1][1], a1, b1); MM(acc[2][1], a2, b1); MM(acc[3][1], a3, b1); \
    MM(acc[0][2], a0, b2); MM(acc[1][2], a1, b2); MM(acc[2][2], a2, b2); MM(acc[3][2], a3, b2); \
    __builtin_amdgcn_s_setprio(0); \
    if (DOST) { if (t < 128) { WAITV(4); } else { WAITV(3); } } \
    else if (!(LASTT)) { WAITV(0); } \
    if (!(LASTT)) { BAR(); SCHEDB(); } \
  }

template <bool F32OUT>
__global__ __launch_bounds__(256, 3) void k_lstm_gemm97(const u16* __restrict__ A,
                                                        const u16* __restrict__ Bp,
                                                        const float* __restrict__ bias,
                                                        void* __restrict__ outp) {
  __shared__ __align__(16) char lds[3 * LDS_TILE];   // 42 KB
  const int t    = threadIdx.x;
  const int lane = t & 63;
  const int w    = t >> 6;          // 0..3
  const int wr   = w >> 1;          // 0..1 (M half: 64 rows)
  const int wc   = w & 1;           // 0..1 (N half: 48 packed cols = 1 trio)
  const int r16  = lane & 15, kg = lane >> 4;

  // T1: bijective XCD swizzle; grid 32x64 = 2048 = 8 x 256. XCD c owns a
  // 16x16 rect of (N-col, M-band) tiles.
  const int n_hw = blockIdx.y * gridDim.x + blockIdx.x;
  const int c    = n_hw & 7;
  const int wlc  = n_hw >> 3;          // 0..255
  const int bx   = (c & 1) * 16 + (wlc & 15);    // 0..31
  const int by   = (c >> 1) * 16 + (wlc >> 4);   // 0..63
  const int brow = by * BM;
  const int bn0  = bx * BN;

  // per-lane swizzled read bases: slot = kg ^ ((row>>1)&3)
  const int sw   = (r16 >> 1) & 3;
  const int slot = (kg ^ sw) << 4;
  const int aOff = wr * 4096 + r16 * 64 + slot;           // + m*1024
  const int bOff = 8192 + wc * 3072 + r16 * 64 + slot;    // + n*1024

  // staging source (inverse-permuted octet within each 64B row)
  const int srow = t >> 2;
  const int koct = ((t & 3) ^ ((t >> 3) & 3)) << 3;
  const u16* srcA = A  + (size_t)(brow + srow) * KDIM + koct;
  const u16* srcB = Bp + (size_t)(bn0  + srow) * KDIM + koct;

  f32x4 acc[4][3];
#pragma unroll
  for (int m = 0; m < 4; ++m)
#pragma unroll
    for (int n = 0; n < 3; ++n) acc[m][n] = (f32x4){0.f, 0.f, 0.f, 0.f};

  // prologue: stage tiles 0,1 -> bufs 0,1; wait own group0 done; barrier.
  STAGE(0, 0);
  STAGE(1, 1);
  if (t < 128) { WAITV(4); } else { WAITV(3); }
  BAR(); SCHEDB();

  // tiles 0..29 (period-3 buffers), then tail tiles 30, 31.
  for (int k3 = 0; k3 < 10; ++k3) {
    int kt = k3 * 3;
    KSTEP(0, 2, kt + 0, 1, 0);
    KSTEP(1, 0, kt + 1, 1, 0);
    KSTEP(2, 1, kt + 2, 1, 0);
  }
  KSTEP(0, 0, 30, 0, 0);
  KSTEP(1, 0, 31, 0, 1);

  // epilogue: wave owns one gate-trio; lane holds i,g,o in acc[m][0..2].
  {
    int pbase = bn0 + wc * 48;
    float biV = bias[pbase + r16];
    float bgV = bias[pbase + 16 + r16];
    float boV = bias[pbase + 32 + r16];
    int hcol = (2 * bx + wc) * 16 + r16;
#pragma unroll
    for (int m = 0; m < 4; ++m) {
      int rowb = brow + wr * 64 + m * 16 + kg * 4;
#pragma unroll
      for (int r = 0; r < 4; ++r) {
        float vi = acc[m][0][r] + biV;
        float vg = acc[m][1][r] + bgV;
        float vo = acc[m][2][r] + boV;
        float c2 = sigmoid_f(vi) * tanh_f(vg);
        float hv = sigmoid_f(vo) * tanh_f(c2);
        size_t oidx = (size_t)(rowb + r) * 1024 + hcol;
        if (F32OUT) ((float*)outp)[oidx] = hv;
        else        ((u16*)outp)[oidx]   = f2bf(hv);
      }
    }
  }
}

// ---------------- launch ----------------
extern "C" void kernel_launch(void* const* d_in, const int* in_sizes, int n_in,
                              void* d_out, int out_size, void* d_ws, size_t ws_size,
                              hipStream_t stream) {
  const float* x     = (const float*)d_in[0];
  const float* Wih0  = (const float*)d_in[1];
  const float* bih0  = (const float*)d_in[3];
  const float* bhh0  = (const float*)d_in[4];
  const float* Wih12 = (const float*)d_in[5];
  const float* bih12 = (const float*)d_in[7];
  const float* bhh12 = (const float*)d_in[8];

  char* ws = (char*)d_ws;
  u16*   xbf = (u16*)ws;                       // 16,777,216 B
  u16*   h1  = (u16*)(ws + 16777216);          // 16,777,216 B
  u16*   h2  = (u16*)(ws + 33554432);          // 16,777,216 B
  u16*   P3  = (u16*)(ws + 50331648);          // 18,874,368 B
  float* pb3 = (float*)(ws + 69206016);        // 36,864 B

  k_convert_x<<<4096, 256, 0, stream>>>(x, xbf);
  k_pack_w<<<4608, 256, 0, stream>>>(Wih0, Wih12, P3);
  k_pack_bias<<<36, 256, 0, stream>>>(bih0, bhh0, bih12, bhh12, pb3);

  dim3 grid(NP / BN, MROWS / BM);   // (32, 64) = 2048 blocks, 3 blocks/CU
  k_lstm_gemm97<false><<<grid, 256, 0, stream>>>(xbf, P3, pb3, h1);
  k_lstm_gemm97<false><<<grid, 256, 0, stream>>>(h1, P3 + (size_t)NP * KDIM, pb3 + NP, h2);
  k_lstm_gemm97<true ><<<grid, 256, 0, stream>>>(h2, P3 + (size_t)2 * NP * KDIM, pb3 + 2 * NP, d_out);
}

// Round 9
// 197.951 us; speedup vs baseline: 1.8180x; 1.1728x over previous
//
#include <hip/hip_runtime.h>

// LSTMnetwork: 3 sequential stages of h = lstm_act(inp @ Wp^T + b)
// M=8192, K=1024, packed N=3072 (f-gate dropped: i,g,o only).
// BM=256 x BN=384, BK=32, 512 thr (2wr x 4wc waves, wave-tile 128x96,
// acc[8][6] = 192 VGPR). LDS tri-buffer 120KB, 2-deep prefetch, uniform
// 5-load staging groups, counted WAITV(5), 1 barrier/tile. Grid 8x32 =
// 256 blocks = exactly 1 round. T1 XCD 4x8-rect swizzle, T2 xor-swizzle.
// Rationale: LDS reads/tile 176->112KB at same MFMA count; serialized
// (no-overlap) bound alone beats the R5 structure by ~20%.

typedef float f32x4 __attribute__((ext_vector_type(4)));
typedef short short8 __attribute__((ext_vector_type(8)));
typedef unsigned short u16;

#define NP 3072
#define MROWS 8192
#define KDIM 1024
#define BM 256
#define BN 384
#define BK 32
#define LDS_TILE 40960              // A 16KB + B 24KB per buffer; x3 = 120KB

__device__ __forceinline__ u16 f2bf(float f) {
  unsigned u = __float_as_uint(f);
  u += 0x7fffu + ((u >> 16) & 1u);   // RTNE
  return (u16)(u >> 16);
}
__device__ __forceinline__ float sigmoid_f(float x) {
  return 1.0f / (1.0f + __expf(-x));
}
__device__ __forceinline__ float tanh_f(float x) {
  float xc = fminf(fmaxf(x, -15.0f), 15.0f);
  float e = __expf(2.0f * xc);
  return (e - 1.0f) / (e + 1.0f);
}
__device__ __forceinline__ void gload_lds16(const void* g, void* l) {
  __builtin_amdgcn_global_load_lds((const __attribute__((address_space(1))) void*)g,
                                   (__attribute__((address_space(3))) void*)l,
                                   16, 0, 0);
}

// ---------------- pre-passes (unchanged, verified) ----------------

__global__ __launch_bounds__(256) void k_convert_x(const float* __restrict__ x,
                                                   u16* __restrict__ out) {
  int tid = blockIdx.x * 256 + threadIdx.x;
  const float4* src = (const float4*)x + (size_t)tid * 2;
  float4 v0 = src[0], v1 = src[1];
  union { u16 u[8]; uint4 v; } r;
  r.u[0] = f2bf(v0.x); r.u[1] = f2bf(v0.y); r.u[2] = f2bf(v0.z); r.u[3] = f2bf(v0.w);
  r.u[4] = f2bf(v1.x); r.u[5] = f2bf(v1.y); r.u[6] = f2bf(v1.z); r.u[7] = f2bf(v1.w);
  ((uint4*)out)[tid] = r.v;
}

__global__ __launch_bounds__(256) void k_pack_w(const float* __restrict__ Wih0,
                                                const float* __restrict__ Wih12,
                                                u16* __restrict__ P) {
  int tid = blockIdx.x * 256 + threadIdx.x;
  int s   = tid / (NP * 128);
  int rem = tid - s * (NP * 128);
  int p   = rem >> 7;
  int k8  = rem & 127;
  int hb = p / 48;
  int pr = p - hb * 48;
  int gs = pr >> 4;
  int hl = pr & 15;
  int hcol = hb * 16 + hl;
  int dir = hcol >> 9;
  int h   = hcol & 511;
  int og  = (gs == 0) ? 0 : (gs + 1);     // 0->i, 1->g, 2->o
  const float* src;
  if (s == 0)
    src = Wih0 + ((size_t)(dir * 2048 + og * 512 + h)) * 1024 + k8 * 8;
  else
    src = Wih12 + ((size_t)(((s - 1) * 2 + dir) * 2048 + og * 512 + h)) * 1024 + k8 * 8;
  float4 v0 = ((const float4*)src)[0];
  float4 v1 = ((const float4*)src)[1];
  union { u16 u[8]; uint4 v; } r;
  r.u[0] = f2bf(v0.x); r.u[1] = f2bf(v0.y); r.u[2] = f2bf(v0.z); r.u[3] = f2bf(v0.w);
  r.u[4] = f2bf(v1.x); r.u[5] = f2bf(v1.y); r.u[6] = f2bf(v1.z); r.u[7] = f2bf(v1.w);
  ((uint4*)P)[tid] = r.v;
}

__global__ __launch_bounds__(256) void k_pack_bias(const float* __restrict__ bih0,
                                                   const float* __restrict__ bhh0,
                                                   const float* __restrict__ bih12,
                                                   const float* __restrict__ bhh12,
                                                   float* __restrict__ pb) {
  int tid = blockIdx.x * 256 + threadIdx.x;
  if (tid >= 3 * NP) return;
  int s = tid / NP;
  int p = tid - s * NP;
  int hb = p / 48;
  int pr = p - hb * 48;
  int gs = pr >> 4;
  int hl = pr & 15;
  int hcol = hb * 16 + hl;
  int dir = hcol >> 9;
  int h   = hcol & 511;
  int og  = (gs == 0) ? 0 : (gs + 1);
  int j   = og * 512 + h;
  float v;
  if (s == 0) {
    int i = dir * 2048 + j;
    v = bih0[i] + bhh0[i];
  } else {
    int i = ((s - 1) * 2 + dir) * 2048 + j;
    v = bih12[i] + bhh12[i];
  }
  pb[tid] = v;
}

// ---------------- fused GEMM + LSTM activation ----------------

#define BAR()    __builtin_amdgcn_s_barrier()
#define SCHEDB() __builtin_amdgcn_sched_barrier(0)
#define WAITV(N) asm volatile("s_waitcnt vmcnt(" #N ")" ::: "memory")
#define MM(Macc, Aop, Bop) Macc = __builtin_amdgcn_mfma_f32_16x16x32_bf16(Aop, Bop, Macc, 0, 0, 0)

// Stage tile KT into buffer BUF: 5 uniform rounds x 512thr x 16B.
// Linear LDS dest (rule 21), inverse-swizzled source octet (koct).
#define STAGE(BUF, KT) \
  { char* dst = lds + (BUF) * LDS_TILE + t * 16; \
    gload_lds16(srcA + (size_t)(KT) * BK,               dst); \
    gload_lds16(srcA + 128 * KDIM + (size_t)(KT) * BK,  dst + 8192); \
    gload_lds16(srcB + (size_t)(KT) * BK,               dst + 16384); \
    gload_lds16(srcB + 128 * KDIM + (size_t)(KT) * BK,  dst + 24576); \
    gload_lds16(srcB + 256 * KDIM + (size_t)(KT) * BK,  dst + 32768); }

// One K-tile (BK=32 = one k32). 8 A-frags + 6 B-frags (B split 3+3 to bound
// register live range), 48 MFMA. Counted WAITV(5): at tile entry the group
// for tile kt+1 (5 loads) is outstanding; stage adds 5 (kt+2); WAITV(5)
// drains kt+1's group, leaving kt+2's. Tail: kt=30 WAITV(0); kt=31 none.
#define KSTEP(RBUF, SBUF, KT, DOST, LASTT) \
  { \
    if (DOST) { STAGE(SBUF, (KT) + 2); } \
    const char* base = lds + (RBUF) * LDS_TILE; \
    short8 a0 = *(const short8*)(base + aBase); \
    short8 a1 = *(const short8*)(base + aBase + 1024); \
    short8 a2 = *(const short8*)(base + aBase + 2048); \
    short8 a3 = *(const short8*)(base + aBase + 3072); \
    short8 a4 = *(const short8*)(base + aBase + 4096); \
    short8 a5 = *(const short8*)(base + aBase + 5120); \
    short8 a6 = *(const short8*)(base + aBase + 6144); \
    short8 a7 = *(const short8*)(base + aBase + 7168); \
    short8 b0 = *(const short8*)(base + bBase); \
    short8 b1 = *(const short8*)(base + bBase + 1024); \
    short8 b2 = *(const short8*)(base + bBase + 2048); \
    __builtin_amdgcn_s_setprio(1); \
    MM(acc[0][0], a0, b0); MM(acc[1][0], a1, b0); MM(acc[2][0], a2, b0); MM(acc[3][0], a3, b0); \
    MM(acc[4][0], a4, b0); MM(acc[5][0], a5, b0); MM(acc[6][0], a6, b0); MM(acc[7][0], a7, b0); \
    MM(acc[0][1], a0, b1); MM(acc[1][1], a1, b1); MM(acc[2][1], a2, b1); MM(acc[3][1], a3, b1); \
    MM(acc[4][1], a4, b1); MM(acc[5][1], a5, b1); MM(acc[6][1], a6, b1); MM(acc[7][1], a7, b1); \
    MM(acc[0][2], a0, b2); MM(acc[1][2], a1, b2); MM(acc[2][2], a2, b2); MM(acc[3][2], a3, b2); \
    MM(acc[4][2], a4, b2); MM(acc[5][2], a5, b2); MM(acc[6][2], a6, b2); MM(acc[7][2], a7, b2); \
    __builtin_amdgcn_s_setprio(0); \
    b0 = *(const short8*)(base + bBase + 3072); \
    b1 = *(const short8*)(base + bBase + 4096); \
    b2 = *(const short8*)(base + bBase + 5120); \
    __builtin_amdgcn_s_setprio(1); \
    MM(acc[0][3], a0, b0); MM(acc[1][3], a1, b0); MM(acc[2][3], a2, b0); MM(acc[3][3], a3, b0); \
    MM(acc[4][3], a4, b0); MM(acc[5][3], a5, b0); MM(acc[6][3], a6, b0); MM(acc[7][3], a7, b0); \
    MM(acc[0][4], a0, b1); MM(acc[1][4], a1, b1); MM(acc[2][4], a2, b1); MM(acc[3][4], a3, b1); \
    MM(acc[4][4], a4, b1); MM(acc[5][4], a5, b1); MM(acc[6][4], a6, b1); MM(acc[7][4], a7, b1); \
    MM(acc[0][5], a0, b2); MM(acc[1][5], a1, b2); MM(acc[2][5], a2, b2); MM(acc[3][5], a3, b2); \
    MM(acc[4][5], a4, b2); MM(acc[5][5], a5, b2); MM(acc[6][5], a6, b2); MM(acc[7][5], a7, b2); \
    __builtin_amdgcn_s_setprio(0); \
    if (DOST) { WAITV(5); } \
    else if (!(LASTT)) { WAITV(0); } \
    if (!(LASTT)) { BAR(); SCHEDB(); } \
  }

template <bool F32OUT>
__global__ __launch_bounds__(512, 2) void k_lstm_gemmW(const u16* __restrict__ A,
                                                       const u16* __restrict__ Bp,
                                                       const float* __restrict__ bias,
                                                       void* __restrict__ outp) {
  __shared__ __align__(16) char lds[3 * LDS_TILE];   // 120 KB
  const int t    = threadIdx.x;
  const int lane = t & 63;
  const int w    = t >> 6;          // 0..7
  const int wr   = w >> 2;          // 0..1 (M half: 128 rows)
  const int wc   = w & 3;           // 0..3 (N quarter: 96 packed cols = 2 trios)
  const int r16  = lane & 15, kg = lane >> 4;

  // T1: bijective XCD swizzle; grid 8x32 = 256 = 8 XCDs x 32. XCD c owns a
  // 4x8 rect (4 N-cols x 8 M-bands): B-slab 3MB, A-band 4MB per XCD.
  const int n_hw = blockIdx.y * gridDim.x + blockIdx.x;
  const int c    = n_hw & 7;
  const int wlc  = n_hw >> 3;          // 0..31
  const int bx   = (c & 1) * 4 + (wlc & 3);    // 0..7
  const int by   = (c >> 1) * 8 + (wlc >> 2);  // 0..31
  const int brow = by * BM;
  const int bn0  = bx * BN;

  // per-lane swizzled read bases: slot = kg ^ ((r16>>1)&3); 64B rows.
  const int slot = (kg ^ ((r16 >> 1) & 3)) << 4;
  const int aBase = wr * 8192 + r16 * 64 + slot;            // + m*1024, m 0..7
  const int bBase = 16384 + wc * 6144 + r16 * 64 + slot;    // + n*1024, n 0..5

  // staging source (inverse-permuted octet within each 64B row)
  const int srow = t >> 2;                          // 0..127
  const int koct = ((t & 3) ^ ((t >> 3) & 3)) << 3;
  const u16* srcA = A  + (size_t)(brow + srow) * KDIM + koct;
  const u16* srcB = Bp + (size_t)(bn0  + srow) * KDIM + koct;

  f32x4 acc[8][6];
#pragma unroll
  for (int m = 0; m < 8; ++m)
#pragma unroll
    for (int n = 0; n < 6; ++n) acc[m][n] = (f32x4){0.f, 0.f, 0.f, 0.f};

  // prologue: stage tiles 0,1 -> bufs 0,1; drain tile0's group; barrier.
  STAGE(0, 0);
  STAGE(1, 1);
  WAITV(5);
  BAR(); SCHEDB();

  // tiles 0..29 (period-3 buffers), then tail tiles 30, 31.
  for (int k3 = 0; k3 < 10; ++k3) {
    int kt = k3 * 3;
    KSTEP(0, 2, kt + 0, 1, 0);
    KSTEP(1, 0, kt + 1, 1, 0);
    KSTEP(2, 1, kt + 2, 1, 0);
  }
  KSTEP(0, 0, 30, 0, 0);
  KSTEP(1, 0, 31, 0, 1);

  // epilogue: wave owns 2 gate-trios (n = trio*3 + {i,g,o}).
#pragma unroll
  for (int trio = 0; trio < 2; ++trio) {
    int pbase = bn0 + wc * 96 + trio * 48;
    float biV = bias[pbase + r16];
    float bgV = bias[pbase + 16 + r16];
    float boV = bias[pbase + 32 + r16];
    int hcol = (bx * 8 + wc * 2 + trio) * 16 + r16;
#pragma unroll
    for (int m = 0; m < 8; ++m) {
      int rowb = brow + wr * 128 + m * 16 + kg * 4;
#pragma unroll
      for (int r = 0; r < 4; ++r) {
        float vi = acc[m][trio * 3 + 0][r] + biV;
        float vg = acc[m][trio * 3 + 1][r] + bgV;
        float vo = acc[m][trio * 3 + 2][r] + boV;
        float c2 = sigmoid_f(vi) * tanh_f(vg);
        float hv = sigmoid_f(vo) * tanh_f(c2);
        size_t oidx = (size_t)(rowb + r) * 1024 + hcol;
        if (F32OUT) ((float*)outp)[oidx] = hv;
        else        ((u16*)outp)[oidx]   = f2bf(hv);
      }
    }
  }
}

// ---------------- launch ----------------
extern "C" void kernel_launch(void* const* d_in, const int* in_sizes, int n_in,
                              void* d_out, int out_size, void* d_ws, size_t ws_size,
                              hipStream_t stream) {
  const float* x     = (const float*)d_in[0];
  const float* Wih0  = (const float*)d_in[1];
  const float* bih0  = (const float*)d_in[3];
  const float* bhh0  = (const float*)d_in[4];
  const float* Wih12 = (const float*)d_in[5];
  const float* bih12 = (const float*)d_in[7];
  const float* bhh12 = (const float*)d_in[8];

  char* ws = (char*)d_ws;
  u16*   xbf = (u16*)ws;                       // 16,777,216 B
  u16*   h1  = (u16*)(ws + 16777216);          // 16,777,216 B
  u16*   h2  = (u16*)(ws + 33554432);          // 16,777,216 B
  u16*   P3  = (u16*)(ws + 50331648);          // 18,874,368 B
  float* pb3 = (float*)(ws + 69206016);        // 36,864 B

  k_convert_x<<<4096, 256, 0, stream>>>(x, xbf);
  k_pack_w<<<4608, 256, 0, stream>>>(Wih0, Wih12, P3);
  k_pack_bias<<<36, 256, 0, stream>>>(bih0, bhh0, bih12, bhh12, pb3);

  dim3 grid(NP / BN, MROWS / BM);   // (8, 32) = 256 blocks = 1 exact round
  k_lstm_gemmW<false><<<grid, 512, 0, stream>>>(xbf, P3, pb3, h1);
  k_lstm_gemmW<false><<<grid, 512, 0, stream>>>(h1, P3 + (size_t)NP * KDIM, pb3 + NP, h2);
  k_lstm_gemmW<true ><<<grid, 512, 0, stream>>>(h2, P3 + (size_t)2 * NP * KDIM, pb3 + 2 * NP, d_out);
}